// Round 4
// baseline (165.653 us; speedup 1.0000x reference)
//
#include <hip/hip_runtime.h>
#include <math.h>

#define HID 128
#define SPB 64    // samples per chunk per block
#define TPB 1024  // 16 waves; 2 blocks/CU -> 100% occupancy target
#define GRIDB 512 // 2 blocks per CU, persistent over chunks

typedef __bf16 bf16;
typedef bf16 bf16x8 __attribute__((ext_vector_type(8)));
typedef float floatx4 __attribute__((ext_vector_type(4)));

__device__ __forceinline__ float fast_tanh(float x) {
    float e = __expf(2.0f * x);
    return 1.0f - 2.0f / (e + 1.0f);
}

// Fragment-ordered layouts ([tile][lane] of bf16x8 => contiguous b128):
//   B-frag tile (kt,nt): lane l holds B[k=kt*32+(l>>4)*8+idx][n=nt*16+(l&15)]
//   A-frag tile (mt,kt): lane l holds A[m=mt*16+(l&15)][k=kt*32+(l>>4)*8+idx]
//   C layout: col = lane&15, row = (lane>>4)*4 + reg
// F1 = W2 as GEMM1 B-frags (contraction over W2 rows)
// F2 = W2 as GEMM2 B-frags (contraction over W2 cols, i.e. W2^T operand)

__global__ __launch_bounds__(256)
void prep_w2(const float* __restrict__ W2, bf16* __restrict__ F1, bf16* __restrict__ F2) {
    int e = blockIdx.x * 256 + threadIdx.x; // 0..2047 : one frag line (t,lane)
    int t = e >> 6, lane = e & 63;
    int kt = t >> 3, nt = t & 7;
    int lrow = lane & 15, quad = lane >> 4;
    bf16x8 f;
    #pragma unroll
    for (int idx = 0; idx < 8; ++idx)
        f[idx] = (bf16)W2[(kt * 32 + quad * 8 + idx) * HID + nt * 16 + lrow];
    *reinterpret_cast<bf16x8*>(&F1[e * 8]) = f;
    const float4* rp = reinterpret_cast<const float4*>(
        &W2[(nt * 16 + lrow) * HID + kt * 32 + quad * 8]);
    float4 r0 = rp[0], r1 = rp[1];
    bf16x8 g;
    g[0] = (bf16)r0.x; g[1] = (bf16)r0.y; g[2] = (bf16)r0.z; g[3] = (bf16)r0.w;
    g[4] = (bf16)r1.x; g[5] = (bf16)r1.y; g[6] = (bf16)r1.z; g[7] = (bf16)r1.w;
    *reinterpret_cast<bf16x8*>(&F2[e * 8]) = g;
}

__global__ __launch_bounds__(TPB, 8)
void lnn_main(const float* __restrict__ X,
              const float* __restrict__ W1,
              const float* __restrict__ b1,
              const float* __restrict__ b2,
              const float* __restrict__ W3,
              const bf16* __restrict__ F1,
              const bf16* __restrict__ F2,
              float* __restrict__ out,
              int B, int nchunk)
{
    __shared__ __align__(16) bf16 sW2F[4*8*64*8]; // 32KB: GEMM1 B-frags (static all kernel)
    __shared__ __align__(16) bf16 sH1 [4*4*64*8]; // 16KB: H1 A-frags
    __shared__ __align__(16) bf16 sG2 [4*4*64*8]; // 16KB: G2 A-frags, reused for G1
    __shared__ float sW1s[4][HID];                // SoA
    __shared__ float sB1[HID];
    __shared__ float sB2[HID];
    __shared__ float sW3[HID];
    __shared__ __align__(16) float sFeat[SPB][4];  // s1,c1,s2,c2
    __shared__ __align__(16) float sDV[4][SPB][4]; // dV/dfeat partials per K-quarter

    const int tid   = threadIdx.x;
    const int w     = tid >> 6;
    const int lane  = tid & 63;
    const int lrow  = lane & 15;
    const int lquad = lane >> 4;
    const int mtile = w >> 2;   // 0..3
    const int nq    = w & 3;    // 0..3

    // ---- one-time staging (amortized over nchunk chunks) ----
    if (tid < 512)      ((float*)sW1s)[tid] = W1[tid];
    else if (tid < 640) sB1[tid - 512] = b1[tid - 512];
    else if (tid < 768) sB2[tid - 640] = b2[tid - 640];
    else if (tid < 896) sW3[tid - 768] = W3[tid - 768];

    #pragma unroll
    for (int e = tid; e < 2048; e += TPB) { // vector copy F1 -> LDS (coalesced)
        bf16x8 v = *reinterpret_cast<const bf16x8*>(&F1[e * 8]);
        *reinterpret_cast<bf16x8*>(&sW2F[e * 8]) = v;
    }

    // W1 B-frag for GEMM3 (dV = G1 @ W1^T), K-quarter nq, in registers
    bf16x8 bW1 = {};
    if (lrow < 4) {
        const float4* wp = reinterpret_cast<const float4*>(
            &W1[lrow * HID + nq * 32 + lquad * 8]);
        float4 a = wp[0], b = wp[1];
        bW1[0] = (bf16)a.x; bW1[1] = (bf16)a.y; bW1[2] = (bf16)a.z; bW1[3] = (bf16)a.w;
        bW1[4] = (bf16)b.x; bW1[5] = (bf16)b.y; bW1[6] = (bf16)b.z; bW1[7] = (bf16)b.w;
    }

    #pragma unroll 1
    for (int c = 0; c < nchunk; ++c) {
        const int s0 = (c * GRIDB + (int)blockIdx.x) * SPB;

        // per-chunk state + trig (tid<64; same threads do the epilogue)
        float xz = 0.f, xw = 0.f;
        if (tid < SPB) {
            int g  = s0 + tid;
            int gc = g < B ? g : (B - 1);
            float4 x = reinterpret_cast<const float4*>(X)[gc];
            float s1, c1, s2, c2;
            __sincosf(x.x, &s1, &c1);
            __sincosf(x.y, &s2, &c2);
            sFeat[tid][0] = s1; sFeat[tid][1] = c1;
            sFeat[tid][2] = s2; sFeat[tid][3] = c2;
            xz = x.z; xw = x.w;
        }

        // GEMM2 B-frags: direct global->register (L2-hot), latency hidden by phase1/GEMM1
        bf16x8 bf2[8];
        #pragma unroll
        for (int kt = 0; kt < 4; ++kt)
            #pragma unroll
            for (int n = 0; n < 2; ++n)
                bf2[kt * 2 + n] = *reinterpret_cast<const bf16x8*>(
                    &F2[((kt * 8 + nq * 2 + n) * 64 + lane) * 8]);

        __syncthreads(); // A: sFeat (and, on c==0, weight staging) visible

        // ---- Phase 1: H1 = tanh(feat @ W1 + b1), A-frag tile (mtile, kt=nq) ----
        {
            int srow = mtile * 16 + lrow;
            float f0 = sFeat[srow][0], f1 = sFeat[srow][1];
            float f2 = sFeat[srow][2], f3 = sFeat[srow][3];
            bf16x8 hf;
            #pragma unroll
            for (int idx = 0; idx < 8; ++idx) {
                int j = nq * 32 + lquad * 8 + idx;
                float z = sB1[j] + f0 * sW1s[0][j] + f1 * sW1s[1][j]
                                 + f2 * sW1s[2][j] + f3 * sW1s[3][j];
                hf[idx] = (bf16)fast_tanh(z);
            }
            *reinterpret_cast<bf16x8*>(&sH1[((mtile * 4 + nq) * 64 + lane) * 8]) = hf;
        }
        __syncthreads(); // B: sH1 ready

        // ---- Phase 2: GEMM1  Z2 = H1 @ W2 ----
        floatx4 acc[2];
        acc[0] = floatx4{0.f, 0.f, 0.f, 0.f};
        acc[1] = floatx4{0.f, 0.f, 0.f, 0.f};
        #pragma unroll
        for (int kt = 0; kt < 4; ++kt) {
            bf16x8 a = *reinterpret_cast<const bf16x8*>(&sH1[((mtile * 4 + kt) * 64 + lane) * 8]);
            #pragma unroll
            for (int n = 0; n < 2; ++n) {
                int nt = nq * 2 + n;
                bf16x8 bfr = *reinterpret_cast<const bf16x8*>(&sW2F[((kt * 8 + nt) * 64 + lane) * 8]);
                acc[n] = __builtin_amdgcn_mfma_f32_16x16x32_bf16(a, bfr, acc[n], 0, 0, 0);
            }
        }

        // ---- Phase 3: G2 = (1 - tanh^2(Z2+b2)) * W3, scatter to A-frags ----
        #pragma unroll
        for (int n = 0; n < 2; ++n) {
            int nt = nq * 2 + n;
            int j  = nt * 16 + lrow;
            float bb = sB2[j], w3 = sW3[j];
            int kt2  = j >> 5;
            int lhi  = ((j >> 3) & 3) << 4;
            int idx2 = j & 7;
            #pragma unroll
            for (int r = 0; r < 4; ++r) {
                float h  = fast_tanh(acc[n][r] + bb);
                float g2 = (1.0f - h * h) * w3;
                sG2[((mtile * 4 + kt2) * 64 + ((lquad * 4 + r) | lhi)) * 8 + idx2] = (bf16)g2;
            }
        }
        __syncthreads(); // C: sG2 ready

        // ---- Phase 4: GEMM2  S = G2 @ W2^T (B-frags in registers) ----
        acc[0] = floatx4{0.f, 0.f, 0.f, 0.f};
        acc[1] = floatx4{0.f, 0.f, 0.f, 0.f};
        #pragma unroll
        for (int kt = 0; kt < 4; ++kt) {
            bf16x8 a = *reinterpret_cast<const bf16x8*>(&sG2[((mtile * 4 + kt) * 64 + lane) * 8]);
            #pragma unroll
            for (int n = 0; n < 2; ++n)
                acc[n] = __builtin_amdgcn_mfma_f32_16x16x32_bf16(a, bf2[kt * 2 + n], acc[n], 0, 0, 0);
        }
        __syncthreads(); // D: all sG2 reads done

        // ---- Phase 5: G1 = (1-h1^2)*S, scatter to A-frags (reuse sG2) ----
        #pragma unroll
        for (int n = 0; n < 2; ++n) {
            int nt = nq * 2 + n;
            int i  = nt * 16 + lrow;
            int kt2  = i >> 5;
            int lhi  = ((i >> 3) & 3) << 4;
            int idx2 = i & 7;
            #pragma unroll
            for (int r = 0; r < 4; ++r) {
                int a_off = ((mtile * 4 + kt2) * 64 + ((lquad * 4 + r) | lhi)) * 8 + idx2;
                float h1 = (float)sH1[a_off];
                float g1 = (1.0f - h1 * h1) * acc[n][r];
                sG2[a_off] = (bf16)g1;
            }
        }
        __syncthreads(); // E: G1 ready

        // ---- Phase 6: GEMM3  dV(K-quarter nq) = G1 @ W1^T ----
        {
            bf16x8 a = *reinterpret_cast<const bf16x8*>(&sG2[((mtile * 4 + nq) * 64 + lane) * 8]);
            floatx4 d = __builtin_amdgcn_mfma_f32_16x16x32_bf16(
                a, bW1, floatx4{0.f, 0.f, 0.f, 0.f}, 0, 0, 0);
            if (lrow < 4) {
                #pragma unroll
                for (int r = 0; r < 4; ++r)
                    sDV[nq][mtile * 16 + lquad * 4 + r][lrow] = d[r];
            }
        }
        __syncthreads(); // F: sDV ready

        // ---- Phase 7: analytic dynamics + 2x2 solve (tid<64) ----
        if (tid < SPB) {
            int g = s0 + tid;
            if (g < B) {
                float4 d0 = *reinterpret_cast<const float4*>(&sDV[0][tid][0]);
                float4 d1 = *reinterpret_cast<const float4*>(&sDV[1][tid][0]);
                float4 d2 = *reinterpret_cast<const float4*>(&sDV[2][tid][0]);
                float4 d3 = *reinterpret_cast<const float4*>(&sDV[3][tid][0]);
                float dV0 = d0.x + d1.x + d2.x + d3.x;
                float dV1 = d0.y + d1.y + d2.y + d3.y;
                float dV2 = d0.z + d1.z + d2.z + d3.z;
                float dV3 = d0.w + d1.w + d2.w + d3.w;
                float s1 = sFeat[tid][0], c1 = sFeat[tid][1];
                float s2 = sFeat[tid][2], c2 = sFeat[tid][3];
                float w1 = xz, w2 = xw;
                float cosD = c1 * c2 + s1 * s2;
                float sinD = s1 * c2 - c1 * s2;
                float dVt1 = dV0 * c1 - dV1 * s1;   // dV/dt1
                float dVt2 = dV2 * c2 - dV3 * s2;   // dV/dt2
                float sT = w1 * w2 * sinD;          // dT/dt1 = -sT, dT/dt2 = +sT
                float cw = sinD * (w2 - w1);
                float rhs1 = (-sT - dVt1) - w2 * cw;
                float rhs2 = ( sT - dVt2) - w1 * cw;
                float det = 2.0f - cosD * cosD;     // det(M) in [1,2]
                float inv = 1.0f / det;
                float qdd1 = (rhs1 - cosD * rhs2) * inv;
                float qdd2 = (2.0f * rhs2 - cosD * rhs1) * inv;
                *reinterpret_cast<float4*>(&out[4 * g]) = make_float4(w1, w2, qdd1, qdd2);
            }
        }
    }
}

extern "C" void kernel_launch(void* const* d_in, const int* in_sizes, int n_in,
                              void* d_out, int out_size, void* d_ws, size_t ws_size,
                              hipStream_t stream) {
    const float* X  = (const float*)d_in[0];
    const float* W1 = (const float*)d_in[1];
    const float* b1 = (const float*)d_in[2];
    const float* W2 = (const float*)d_in[3];
    const float* b2 = (const float*)d_in[4];
    const float* W3 = (const float*)d_in[5];
    // d_in[6] = b3: constant offset on V, vanishes in all gradients
    float* out = (float*)d_out;
    int B = in_sizes[0] / 4;

    bf16* F1 = (bf16*)d_ws;          // 16384 bf16 = 32KB
    bf16* F2 = F1 + 16384;           // 32KB

    prep_w2<<<8, 256, 0, stream>>>(W2, F1, F2);

    int nchunk = (B + GRIDB * SPB - 1) / (GRIDB * SPB);
    lnn_main<<<GRIDB, TPB, 0, stream>>>(X, W1, b1, b2, W3, F1, F2, out, B, nchunk);
}

// Round 5
// 143.587 us; speedup vs baseline: 1.1537x; 1.1537x over previous
//
#include <hip/hip_runtime.h>
#include <math.h>

#define HID 128
#define SPB 64    // samples per chunk per block
#define TPB 1024  // 16 waves; 2 blocks/CU
#define GRIDB 512 // persistent: 2 blocks per CU

typedef __bf16 bf16;
typedef bf16 bf16x8 __attribute__((ext_vector_type(8)));
typedef float floatx4 __attribute__((ext_vector_type(4)));

__device__ __forceinline__ float fast_tanh(float x) {
    float e = __expf(2.0f * x);
    return 1.0f - 2.0f / (e + 1.0f);
}

// Fragment-ordered layouts ([tile][lane] of bf16x8 => contiguous b128):
//   B-frag tile (kt,nt): lane l holds B[k=kt*32+(l>>4)*8+idx][n=nt*16+(l&15)]
//   A-frag tile (mt,kt): lane l holds A[m=mt*16+(l&15)][k=kt*32+(l>>4)*8+idx]
//   C layout: col = lane&15, row = (lane>>4)*4 + reg
// Wave w: mtile = w>>2, nq = w&3. Key invariant: phase-3/5 scatters of wave
// (mtile,nq) write exactly sG2 tile (mtile,nq) => GEMM3 needs no barrier.

__global__ __launch_bounds__(TPB, 8)
void lnn_kernel(const float* __restrict__ X,
                const float* __restrict__ W1,
                const float* __restrict__ b1,
                const float* __restrict__ b2,
                const float* __restrict__ W3,
                const float* __restrict__ W2,
                float* __restrict__ out,
                int B, int nchunk)
{
    // 64KB: [0,16384)=W2 GEMM1 B-frags (static); [16384,24576)=H1; [24576,32768)=G2
    __shared__ __align__(16) bf16 sBuf[32768];
    __shared__ __align__(16) float4 sW1c[HID];      // sW1c[j] = {W1[0][j],..,W1[3][j]}
    __shared__ float sB1[HID], sB2[HID], sW3[HID];
    __shared__ __align__(16) float sFeat[2][SPB][4]; // double-buffered s1,c1,s2,c2
    __shared__ float sQd[2][SPB][2];                 // double-buffered w1,w2
    __shared__ __align__(16) float sDV[4][SPB][4];   // dV/dfeat partials per K-quarter

    bf16* const sW2F = sBuf;
    bf16* const sH1  = sBuf + 16384;
    bf16* const sG2  = sBuf + 24576;
    bf16* const sBnc = sBuf + 16384; // 32KB bounce spanning H1+G2 (pre-loop only)

    const int tid   = threadIdx.x;
    const int w     = tid >> 6;
    const int lane  = tid & 63;
    const int lrow  = lane & 15;
    const int lquad = lane >> 4;
    const int mtile = w >> 2;   // 0..3
    const int nq    = w & 3;    // 0..3

    // ---------------- one-time staging (amortized over nchunk) ----------------
    if (tid < HID) {
        sW1c[tid] = make_float4(W1[tid], W1[HID + tid], W1[2*HID + tid], W1[3*HID + tid]);
        sB1[tid]  = b1[tid];
    } else if (tid < 2 * HID) {
        sB2[tid - HID] = b2[tid - HID];
        sW3[tid - HID] = W3[tid - HID];
    }

    // Build both W2 fragment orientations from cached global W2 (2 lines/thread)
    #pragma unroll
    for (int tt = 0; tt < 2; ++tt) {
        int e = tid + tt * TPB;       // 0..2047 frag lines
        int t = e >> 6, l = e & 63;
        int kt = t >> 3, nt = t & 7;
        int lr = l & 15, q = l >> 4;
        bf16x8 f; // GEMM1 orientation (contract over W2 rows): gather
        #pragma unroll
        for (int idx = 0; idx < 8; ++idx)
            f[idx] = (bf16)W2[(kt * 32 + q * 8 + idx) * HID + nt * 16 + lr];
        *reinterpret_cast<bf16x8*>(&sW2F[e * 8]) = f;
        // GEMM2 orientation (W2^T operand): row-contiguous float4 loads
        const float4* rp = reinterpret_cast<const float4*>(
            &W2[(nt * 16 + lr) * HID + kt * 32 + q * 8]);
        float4 r0 = rp[0], r1 = rp[1];
        bf16x8 g;
        g[0]=(bf16)r0.x; g[1]=(bf16)r0.y; g[2]=(bf16)r0.z; g[3]=(bf16)r0.w;
        g[4]=(bf16)r1.x; g[5]=(bf16)r1.y; g[6]=(bf16)r1.z; g[7]=(bf16)r1.w;
        *reinterpret_cast<bf16x8*>(&sBnc[e * 8]) = g;
    }

    // W1 B-frag for GEMM3 (dV = G1 @ W1^T), K-quarter nq, in registers
    bf16x8 bW1 = {};
    if (lrow < 4) {
        const float4* wp = reinterpret_cast<const float4*>(
            &W1[lrow * HID + nq * 32 + lquad * 8]);
        float4 a = wp[0], b = wp[1];
        bW1[0]=(bf16)a.x; bW1[1]=(bf16)a.y; bW1[2]=(bf16)a.z; bW1[3]=(bf16)a.w;
        bW1[4]=(bf16)b.x; bW1[5]=(bf16)b.y; bW1[6]=(bf16)b.z; bW1[7]=(bf16)b.w;
    }

    // chunk-0 state prefetch (wave 15)
    if (tid >= TPB - SPB) {
        int s  = tid - (TPB - SPB);
        int g  = (int)blockIdx.x * SPB + s;
        int gc = g < B ? g : (B - 1);
        float4 x = reinterpret_cast<const float4*>(X)[gc];
        float s1, c1, s2, c2;
        __sincosf(x.x, &s1, &c1);
        __sincosf(x.y, &s2, &c2);
        sFeat[0][s][0]=s1; sFeat[0][s][1]=c1; sFeat[0][s][2]=s2; sFeat[0][s][3]=c2;
        sQd[0][s][0]=x.z;  sQd[0][s][1]=x.w;
    }
    __syncthreads(); // bounce + weights + chunk-0 state visible

    // GEMM2 B-frags -> registers via LDS bounce (bounce region is clobbered in
    // the loop, so the compiler MUST keep these 8 frags resident in VGPRs)
    bf16x8 bf2[8];
    #pragma unroll
    for (int kt = 0; kt < 4; ++kt)
        #pragma unroll
        for (int n = 0; n < 2; ++n)
            bf2[kt * 2 + n] = *reinterpret_cast<const bf16x8*>(
                &sBnc[((kt * 8 + nq * 2 + n) * 64 + lane) * 8]);
    __syncthreads(); // all bounce reads done before H1/G2 regions are reused

    #pragma unroll 1
    for (int c = 0; c < nchunk; ++c) {
        const int par = c & 1;
        const int s0  = (c * GRIDB + (int)blockIdx.x) * SPB;

        // ---- Phase 1: H1 = tanh(feat @ W1 + b1), A-frag tile (mtile, kt=nq) ----
        {
            int srow = mtile * 16 + lrow;
            float f0 = sFeat[par][srow][0], f1 = sFeat[par][srow][1];
            float f2 = sFeat[par][srow][2], f3 = sFeat[par][srow][3];
            bf16x8 hf;
            #pragma unroll
            for (int idx = 0; idx < 8; ++idx) {
                int j = nq * 32 + lquad * 8 + idx;
                float4 wc = sW1c[j];
                float z = sB1[j] + f0 * wc.x + f1 * wc.y + f2 * wc.z + f3 * wc.w;
                hf[idx] = (bf16)fast_tanh(z);
            }
            *reinterpret_cast<bf16x8*>(&sH1[((mtile * 4 + nq) * 64 + lane) * 8]) = hf;
        }
        __syncthreads(); // B: sH1 ready

        // ---- GEMM1: Z2 = H1 @ W2 ----
        floatx4 acc0 = {0.f,0.f,0.f,0.f}, acc1 = {0.f,0.f,0.f,0.f};
        #pragma unroll
        for (int kt = 0; kt < 4; ++kt) {
            bf16x8 a  = *reinterpret_cast<const bf16x8*>(&sH1[((mtile*4 + kt)*64 + lane)*8]);
            bf16x8 b0 = *reinterpret_cast<const bf16x8*>(&sW2F[((kt*8 + nq*2    )*64 + lane)*8]);
            bf16x8 b1v= *reinterpret_cast<const bf16x8*>(&sW2F[((kt*8 + nq*2 + 1)*64 + lane)*8]);
            acc0 = __builtin_amdgcn_mfma_f32_16x16x32_bf16(a, b0,  acc0, 0, 0, 0);
            acc1 = __builtin_amdgcn_mfma_f32_16x16x32_bf16(a, b1v, acc1, 0, 0, 0);
        }

        // ---- Phase 3: G2 = (1-tanh^2(Z2+b2))*W3, scatter into own tile (mtile,nq) ----
        #pragma unroll
        for (int n = 0; n < 2; ++n) {
            int j   = (nq * 2 + n) * 16 + lrow;
            float bb = sB2[j], w3 = sW3[j];
            int lhi  = (n * 2 + (lrow >> 3)) << 4;
            int idx2 = lrow & 7;
            const floatx4& av = n ? acc1 : acc0;
            #pragma unroll
            for (int r = 0; r < 4; ++r) {
                float h = fast_tanh(av[r] + bb);
                sG2[((mtile*4 + nq)*64 + ((lquad*4 + r) | lhi))*8 + idx2] =
                    (bf16)((1.0f - h * h) * w3);
            }
        }
        __syncthreads(); // C: sG2 ready

        // ---- GEMM2: S = G2 @ W2^T (B-frags resident in registers) ----
        acc0 = floatx4{0.f,0.f,0.f,0.f}; acc1 = floatx4{0.f,0.f,0.f,0.f};
        #pragma unroll
        for (int kt = 0; kt < 4; ++kt) {
            bf16x8 a = *reinterpret_cast<const bf16x8*>(&sG2[((mtile*4 + kt)*64 + lane)*8]);
            acc0 = __builtin_amdgcn_mfma_f32_16x16x32_bf16(a, bf2[kt*2    ], acc0, 0, 0, 0);
            acc1 = __builtin_amdgcn_mfma_f32_16x16x32_bf16(a, bf2[kt*2 + 1], acc1, 0, 0, 0);
        }
        __syncthreads(); // D: all cross-wave sG2 reads done

        // ---- Phase 5: G1 = (1-h1^2)*S, scatter into OWN tile (no barrier needed) ----
        #pragma unroll
        for (int n = 0; n < 2; ++n) {
            int lhi  = (n * 2 + (lrow >> 3)) << 4;
            int idx2 = lrow & 7;
            const floatx4& av = n ? acc1 : acc0;
            #pragma unroll
            for (int r = 0; r < 4; ++r) {
                int a_off = ((mtile*4 + nq)*64 + ((lquad*4 + r) | lhi))*8 + idx2;
                float h1 = (float)sH1[a_off];
                sG2[a_off] = (bf16)((1.0f - h1 * h1) * av[r]);
            }
        }

        // prefetch next chunk's state (wave 15), overlapped with GEMM3
        if (tid >= TPB - SPB && c + 1 < nchunk) {
            int s  = tid - (TPB - SPB);
            int g  = ((c + 1) * GRIDB + (int)blockIdx.x) * SPB + s;
            int gc = g < B ? g : (B - 1);
            float4 x = reinterpret_cast<const float4*>(X)[gc];
            float s1, c1, s2, c2;
            __sincosf(x.x, &s1, &c1);
            __sincosf(x.y, &s2, &c2);
            int np = par ^ 1;
            sFeat[np][s][0]=s1; sFeat[np][s][1]=c1; sFeat[np][s][2]=s2; sFeat[np][s][3]=c2;
            sQd[np][s][0]=x.z;  sQd[np][s][1]=x.w;
        }

        // ---- GEMM3: dV(K-quarter nq) = G1 @ W1^T (same-wave tile, in-wave lgkmcnt) ----
        {
            bf16x8 a = *reinterpret_cast<const bf16x8*>(&sG2[((mtile*4 + nq)*64 + lane)*8]);
            floatx4 d = __builtin_amdgcn_mfma_f32_16x16x32_bf16(
                a, bW1, floatx4{0.f,0.f,0.f,0.f}, 0, 0, 0);
            if (lrow < 4) {
                #pragma unroll
                for (int r = 0; r < 4; ++r)
                    sDV[nq][mtile*16 + lquad*4 + r][lrow] = d[r];
            }
        }
        __syncthreads(); // F: sDV + next-chunk state visible

        // ---- Epilogue: analytic dynamics + 2x2 solve (wave 0) ----
        if (tid < SPB) {
            int g = s0 + tid;
            if (g < B) {
                float4 d0 = *reinterpret_cast<const float4*>(&sDV[0][tid][0]);
                float4 d1 = *reinterpret_cast<const float4*>(&sDV[1][tid][0]);
                float4 d2 = *reinterpret_cast<const float4*>(&sDV[2][tid][0]);
                float4 d3 = *reinterpret_cast<const float4*>(&sDV[3][tid][0]);
                float dV0 = d0.x + d1.x + d2.x + d3.x;
                float dV1 = d0.y + d1.y + d2.y + d3.y;
                float dV2 = d0.z + d1.z + d2.z + d3.z;
                float dV3 = d0.w + d1.w + d2.w + d3.w;
                float s1 = sFeat[par][tid][0], c1 = sFeat[par][tid][1];
                float s2 = sFeat[par][tid][2], c2 = sFeat[par][tid][3];
                float w1 = sQd[par][tid][0],  w2 = sQd[par][tid][1];
                float cosD = c1 * c2 + s1 * s2;
                float sinD = s1 * c2 - c1 * s2;
                float dVt1 = dV0 * c1 - dV1 * s1;   // dV/dt1
                float dVt2 = dV2 * c2 - dV3 * s2;   // dV/dt2
                float sT = w1 * w2 * sinD;          // dT/dt1 = -sT, dT/dt2 = +sT
                float cw = sinD * (w2 - w1);
                float rhs1 = (-sT - dVt1) - w2 * cw;
                float rhs2 = ( sT - dVt2) - w1 * cw;
                float det = 2.0f - cosD * cosD;     // det(M) in [1,2]
                float inv = 1.0f / det;
                float qdd1 = (rhs1 - cosD * rhs2) * inv;
                float qdd2 = (2.0f * rhs2 - cosD * rhs1) * inv;
                *reinterpret_cast<float4*>(&out[4 * g]) = make_float4(w1, w2, qdd1, qdd2);
            }
        }
    }
}

extern "C" void kernel_launch(void* const* d_in, const int* in_sizes, int n_in,
                              void* d_out, int out_size, void* d_ws, size_t ws_size,
                              hipStream_t stream) {
    const float* X  = (const float*)d_in[0];
    const float* W1 = (const float*)d_in[1];
    const float* b1 = (const float*)d_in[2];
    const float* W2 = (const float*)d_in[3];
    const float* b2 = (const float*)d_in[4];
    const float* W3 = (const float*)d_in[5];
    // d_in[6] = b3: constant offset on V, vanishes in all gradients
    float* out = (float*)d_out;
    int B = in_sizes[0] / 4;
    int nchunk = (B + GRIDB * SPB - 1) / (GRIDB * SPB);
    lnn_kernel<<<GRIDB, TPB, 0, stream>>>(X, W1, b1, b2, W3, W2, out, B, nchunk);
}

// Round 6
// 99.060 us; speedup vs baseline: 1.6723x; 1.4495x over previous
//
#include <hip/hip_runtime.h>
#include <math.h>

#define HID 128
#define SPB 128   // samples per chunk per block
#define TPB 1024  // 16 waves; 1 persistent block per CU
#define GRIDB 256

typedef __bf16 bf16;
typedef bf16 bf16x8 __attribute__((ext_vector_type(8)));
typedef float floatx4 __attribute__((ext_vector_type(4)));

__device__ __forceinline__ float fast_tanh(float x) {
    float e = __expf(2.0f * x);
    return 1.0f - 2.0f / (e + 1.0f);
}

// Fragment-ordered layouts ([tile][lane] of bf16x8 => contiguous b128):
//   B-frag tile (kt,nt): lane l holds B[k=kt*32+(l>>4)*8+idx][n=nt*16+(l&15)]
//   A-frag tile (mt,kt): lane l holds A[m=mt*16+(l&15)][k=kt*32+(l>>4)*8+idx]
//   C layout: col = lane&15, row = (lane>>4)*4 + reg
// Wave w: mtile = w>>1 (0..7, 16-sample stripe), nh = w&1 (n-half: 4 n-tiles,
// and K-half for GEMM3). Invariant: phase-3/5 scatters of wave (mtile,nh)
// write exactly sG2/sH1 tiles (mtile, kt in {2nh,2nh+1}) => GEMM3 needs no
// barrier after phase 5 (same-wave data, in-wave lgkmcnt ordering).

__global__ __launch_bounds__(TPB, 4)
void lnn_kernel(const float* __restrict__ X,
                const float* __restrict__ W1,
                const float* __restrict__ b1,
                const float* __restrict__ b2,
                const float* __restrict__ W3,
                const float* __restrict__ W2,
                float* __restrict__ out,
                int B, int nchunk)
{
    // ~142 KB total (gfx950: 160 KB/WG) -> 1 block/CU, no spills, no restaging
    __shared__ __align__(16) bf16 sW2F1[16384]; // 32KB GEMM1 B-frags (static)
    __shared__ __align__(16) bf16 sW2F2[16384]; // 32KB GEMM2 B-frags (static)
    __shared__ __align__(16) bf16 sH1 [16384];  // 32KB H1 A-frags [mt*4+kt][lane][8]
    __shared__ __align__(16) bf16 sG2 [16384];  // 32KB G2/G1 A-frags
    __shared__ __align__(16) float4 sW1c[HID];  // sW1c[j] = {W1[0][j],..,W1[3][j]}
    __shared__ float sB1[HID], sB2[HID], sW3[HID];
    __shared__ __align__(16) float sFeat[2][SPB][4]; // dbuf s1,c1,s2,c2
    __shared__ float sQd[2][SPB][2];                 // dbuf w1,w2
    __shared__ __align__(16) float sDV[2][SPB][4];   // dV partials per K-half

    const int tid   = threadIdx.x;
    const int w     = tid >> 6;
    const int lane  = tid & 63;
    const int lrow  = lane & 15;
    const int lquad = lane >> 4;
    const int mtile = w >> 1;   // 0..7
    const int nh    = w & 1;    // 0..1

    // ---------------- one-time staging (amortized over nchunk) ----------------
    if (tid < HID) {
        sW1c[tid] = make_float4(W1[tid], W1[HID + tid], W1[2*HID + tid], W1[3*HID + tid]);
        sB1[tid]  = b1[tid];
    } else if (tid < 2 * HID) {
        sB2[tid - HID] = b2[tid - HID];
        sW3[tid - HID] = W3[tid - HID];
    }

    // Both W2 fragment orientations -> static LDS (2 frag lines per thread)
    #pragma unroll
    for (int tt = 0; tt < 2; ++tt) {
        int e = tid + tt * TPB;       // 0..2047 frag lines
        int t = e >> 6, l = e & 63;
        int kt = t >> 3, nt = t & 7;
        int lr = l & 15, q = l >> 4;
        bf16x8 f; // GEMM1 orientation (contract over W2 rows): strided gather
        #pragma unroll
        for (int idx = 0; idx < 8; ++idx)
            f[idx] = (bf16)W2[(kt * 32 + q * 8 + idx) * HID + nt * 16 + lr];
        *reinterpret_cast<bf16x8*>(&sW2F1[e * 8]) = f;
        // GEMM2 orientation (W2^T operand): row-contiguous float4 loads
        const float4* rp = reinterpret_cast<const float4*>(
            &W2[(nt * 16 + lr) * HID + kt * 32 + q * 8]);
        float4 r0 = rp[0], r1 = rp[1];
        bf16x8 g;
        g[0]=(bf16)r0.x; g[1]=(bf16)r0.y; g[2]=(bf16)r0.z; g[3]=(bf16)r0.w;
        g[4]=(bf16)r1.x; g[5]=(bf16)r1.y; g[6]=(bf16)r1.z; g[7]=(bf16)r1.w;
        *reinterpret_cast<bf16x8*>(&sW2F2[e * 8]) = g;
    }

    // W1 B-frags for GEMM3 (dV = G1 @ W1^T), K-blocks {2nh, 2nh+1}, 8 VGPRs
    bf16x8 bW1[2] = {{}, {}};
    if (lrow < 4) {
        #pragma unroll
        for (int h = 0; h < 2; ++h) {
            const float4* wp = reinterpret_cast<const float4*>(
                &W1[lrow * HID + (nh * 2 + h) * 32 + lquad * 8]);
            float4 a = wp[0], b = wp[1];
            bW1[h][0]=(bf16)a.x; bW1[h][1]=(bf16)a.y; bW1[h][2]=(bf16)a.z; bW1[h][3]=(bf16)a.w;
            bW1[h][4]=(bf16)b.x; bW1[h][5]=(bf16)b.y; bW1[h][6]=(bf16)b.z; bW1[h][7]=(bf16)b.w;
        }
    }

    // chunk-0 state prefetch (waves 14,15)
    if (tid >= TPB - SPB) {
        int s  = tid - (TPB - SPB);
        int g  = (int)blockIdx.x * SPB + s;
        int gc = g < B ? g : (B - 1);
        float4 x = reinterpret_cast<const float4*>(X)[gc];
        float s1, c1, s2, c2;
        __sincosf(x.x, &s1, &c1);
        __sincosf(x.y, &s2, &c2);
        sFeat[0][s][0]=s1; sFeat[0][s][1]=c1; sFeat[0][s][2]=s2; sFeat[0][s][3]=c2;
        sQd[0][s][0]=x.z;  sQd[0][s][1]=x.w;
    }
    __syncthreads(); // weights + chunk-0 state visible

    #pragma unroll 1
    for (int c = 0; c < nchunk; ++c) {
        const int par = c & 1;
        const int s0  = (c * GRIDB + (int)blockIdx.x) * SPB;

        // ---- Phase 1: H1 = tanh(feat @ W1 + b1), tiles (mtile, kt=2nh..2nh+1) ----
        {
            int srow = mtile * 16 + lrow;
            float f0 = sFeat[par][srow][0], f1 = sFeat[par][srow][1];
            float f2 = sFeat[par][srow][2], f3 = sFeat[par][srow][3];
            #pragma unroll
            for (int h = 0; h < 2; ++h) {
                int kt = nh * 2 + h;
                bf16x8 hf;
                #pragma unroll
                for (int idx = 0; idx < 8; ++idx) {
                    int j = kt * 32 + lquad * 8 + idx;
                    float4 wc = sW1c[j];
                    float z = sB1[j] + f0 * wc.x + f1 * wc.y + f2 * wc.z + f3 * wc.w;
                    hf[idx] = (bf16)fast_tanh(z);
                }
                *reinterpret_cast<bf16x8*>(&sH1[((mtile * 4 + kt) * 64 + lane) * 8]) = hf;
            }
        }
        __syncthreads(); // B: sH1 ready

        // ---- GEMM1: Z2 = H1 @ W2  (1 m-tile x 4 n-tiles per wave) ----
        floatx4 acc[4];
        #pragma unroll
        for (int n = 0; n < 4; ++n) acc[n] = floatx4{0.f,0.f,0.f,0.f};
        #pragma unroll
        for (int kt = 0; kt < 4; ++kt) {
            bf16x8 a = *reinterpret_cast<const bf16x8*>(&sH1[((mtile*4 + kt)*64 + lane)*8]);
            #pragma unroll
            for (int n = 0; n < 4; ++n) {
                int nt = nh * 4 + n;
                bf16x8 bfr = *reinterpret_cast<const bf16x8*>(&sW2F1[((kt*8 + nt)*64 + lane)*8]);
                acc[n] = __builtin_amdgcn_mfma_f32_16x16x32_bf16(a, bfr, acc[n], 0, 0, 0);
            }
        }

        // ---- Phase 3: G2 = (1-tanh^2(Z2+b2))*W3, scatter into own kt-half ----
        #pragma unroll
        for (int n = 0; n < 4; ++n) {
            int j    = (nh * 4 + n) * 16 + lrow;
            float bb = sB2[j], w3 = sW3[j];
            int kt2  = j >> 5;
            int lhi  = ((j >> 3) & 3) << 4;
            int idx2 = j & 7;
            #pragma unroll
            for (int r = 0; r < 4; ++r) {
                float h = fast_tanh(acc[n][r] + bb);
                sG2[((mtile*4 + kt2)*64 + ((lquad*4 + r) | lhi))*8 + idx2] =
                    (bf16)((1.0f - h * h) * w3);
            }
        }
        __syncthreads(); // C: sG2 ready

        // ---- GEMM2: S = G2 @ W2^T ----
        #pragma unroll
        for (int n = 0; n < 4; ++n) acc[n] = floatx4{0.f,0.f,0.f,0.f};
        #pragma unroll
        for (int kt = 0; kt < 4; ++kt) {
            bf16x8 a = *reinterpret_cast<const bf16x8*>(&sG2[((mtile*4 + kt)*64 + lane)*8]);
            #pragma unroll
            for (int n = 0; n < 4; ++n) {
                int nt = nh * 4 + n;
                bf16x8 bfr = *reinterpret_cast<const bf16x8*>(&sW2F2[((kt*8 + nt)*64 + lane)*8]);
                acc[n] = __builtin_amdgcn_mfma_f32_16x16x32_bf16(a, bfr, acc[n], 0, 0, 0);
            }
        }
        __syncthreads(); // D: all cross-wave sG2 reads done

        // ---- Phase 5: G1 = (1-h1^2)*S, scatter into OWN kt-half (no barrier) ----
        #pragma unroll
        for (int n = 0; n < 4; ++n) {
            int i    = (nh * 4 + n) * 16 + lrow;
            int kt2  = i >> 5;
            int lhi  = ((i >> 3) & 3) << 4;
            int idx2 = i & 7;
            #pragma unroll
            for (int r = 0; r < 4; ++r) {
                int a_off = ((mtile*4 + kt2)*64 + ((lquad*4 + r) | lhi))*8 + idx2;
                float h1 = (float)sH1[a_off];
                sG2[a_off] = (bf16)((1.0f - h1 * h1) * acc[n][r]);
            }
        }

        // prefetch next chunk's state (waves 14,15), overlapped with GEMM3
        if (tid >= TPB - SPB && c + 1 < nchunk) {
            int s  = tid - (TPB - SPB);
            int g  = ((c + 1) * GRIDB + (int)blockIdx.x) * SPB + s;
            int gc = g < B ? g : (B - 1);
            float4 x = reinterpret_cast<const float4*>(X)[gc];
            float s1, c1, s2, c2;
            __sincosf(x.x, &s1, &c1);
            __sincosf(x.y, &s2, &c2);
            int np = par ^ 1;
            sFeat[np][s][0]=s1; sFeat[np][s][1]=c1; sFeat[np][s][2]=s2; sFeat[np][s][3]=c2;
            sQd[np][s][0]=x.z;  sQd[np][s][1]=x.w;
        }

        // ---- GEMM3: dV(K-half nh) = G1 @ W1^T (same-wave tiles) ----
        {
            floatx4 d = floatx4{0.f,0.f,0.f,0.f};
            #pragma unroll
            for (int h = 0; h < 2; ++h) {
                int kt = nh * 2 + h;
                bf16x8 a = *reinterpret_cast<const bf16x8*>(&sG2[((mtile*4 + kt)*64 + lane)*8]);
                d = __builtin_amdgcn_mfma_f32_16x16x32_bf16(a, bW1[h], d, 0, 0, 0);
            }
            if (lrow < 4) { // col = feat index k, rows = 4 samples
                #pragma unroll
                for (int r = 0; r < 4; ++r)
                    sDV[nh][mtile*16 + lquad*4 + r][lrow] = d[r];
            }
        }
        __syncthreads(); // F: sDV + next-chunk state visible

        // ---- Epilogue: analytic dynamics + 2x2 solve (waves 0,1) ----
        if (tid < SPB) {
            int g = s0 + tid;
            if (g < B) {
                float4 d0 = *reinterpret_cast<const float4*>(&sDV[0][tid][0]);
                float4 d1 = *reinterpret_cast<const float4*>(&sDV[1][tid][0]);
                float dV0 = d0.x + d1.x;
                float dV1 = d0.y + d1.y;
                float dV2 = d0.z + d1.z;
                float dV3 = d0.w + d1.w;
                float s1 = sFeat[par][tid][0], c1 = sFeat[par][tid][1];
                float s2 = sFeat[par][tid][2], c2 = sFeat[par][tid][3];
                float w1 = sQd[par][tid][0],  w2 = sQd[par][tid][1];
                float cosD = c1 * c2 + s1 * s2;
                float sinD = s1 * c2 - c1 * s2;
                float dVt1 = dV0 * c1 - dV1 * s1;   // dV/dt1
                float dVt2 = dV2 * c2 - dV3 * s2;   // dV/dt2
                float sT = w1 * w2 * sinD;          // dT/dt1 = -sT, dT/dt2 = +sT
                float cw = sinD * (w2 - w1);
                float rhs1 = (-sT - dVt1) - w2 * cw;
                float rhs2 = ( sT - dVt2) - w1 * cw;
                float det = 2.0f - cosD * cosD;     // det(M) in [1,2]
                float inv = 1.0f / det;
                float qdd1 = (rhs1 - cosD * rhs2) * inv;
                float qdd2 = (2.0f * rhs2 - cosD * rhs1) * inv;
                *reinterpret_cast<float4*>(&out[4 * g]) = make_float4(w1, w2, qdd1, qdd2);
            }
        }
    }
}

extern "C" void kernel_launch(void* const* d_in, const int* in_sizes, int n_in,
                              void* d_out, int out_size, void* d_ws, size_t ws_size,
                              hipStream_t stream) {
    const float* X  = (const float*)d_in[0];
    const float* W1 = (const float*)d_in[1];
    const float* b1 = (const float*)d_in[2];
    const float* W2 = (const float*)d_in[3];
    const float* b2 = (const float*)d_in[4];
    const float* W3 = (const float*)d_in[5];
    // d_in[6] = b3: constant offset on V, vanishes in all gradients
    float* out = (float*)d_out;
    int B = in_sizes[0] / 4;
    int nchunk = (B + GRIDB * SPB - 1) / (GRIDB * SPB);
    lnn_kernel<<<GRIDB, TPB, 0, stream>>>(X, W1, b1, b2, W3, W2, out, B, nchunk);
}

// Round 7
// 98.081 us; speedup vs baseline: 1.6890x; 1.0100x over previous
//
#include <hip/hip_runtime.h>
#include <math.h>

#define HID 128
#define SPB 64    // samples per chunk per block
#define TPB 512   // 8 waves; 2 blocks/CU (74.5KB LDS) -> two barrier domains
#define GRIDB 512 // persistent

typedef __bf16 bf16;
typedef bf16 bf16x8 __attribute__((ext_vector_type(8)));
typedef bf16 bf16x4 __attribute__((ext_vector_type(4)));
typedef float floatx4 __attribute__((ext_vector_type(4)));

__device__ __forceinline__ float fast_tanh(float x) {
    float e = __builtin_amdgcn_exp2f(x * 2.885390081777927f); // exp(2x)
    return 1.0f - 2.0f / (e + 1.0f);
}

// ALL-TRANSPOSED formulation. MFMA 16x16x32 layouts:
//   A-frag: lane holds A[m=lane&15][k=quad*8+idx]
//   B-frag: lane holds B[k=quad*8+idx][n=lane&15]
//   C/D:    lane/reg holds D[row=quad*4+reg][col=lane&15]
// GEMM1t: Z2^T = W2^T @ H1^T   (A=W2^T frags in LDS, B=H1^T frags in LDS)
// GEMM2t: S^T  = W2 @ G2^T     (A=W2 rows from GLOBAL->regs, B=G2^T in LDS)
// GEMM3t: dV^T = W1 @ G1^T     (A=W1 reg frag, B=G1^T in LDS, same-wave tiles)
// Key: C rows are 4 consecutive k-indices of the NEXT GEMM's B operand =>
// layout transforms are b64 LDS ops, not u16 scatters.
// Wave w (8 waves): wlo=w&3, whi=w>>2.
//   phase1: st=wlo, kt in {2whi,2whi+1}
//   GEMM1t/phase3: jt in {2wlo,2wlo+1}, st in {2whi,2whi+1}
//   GEMM2t/phase5/GEMM3t: it in {2wlo,2wlo+1} (jt2_own=wlo), st in {2whi,2whi+1}

__global__ __launch_bounds__(TPB, 4)
void lnn_kernel(const float* __restrict__ X,
                const float* __restrict__ W1,
                const float* __restrict__ b1,
                const float* __restrict__ b2,
                const float* __restrict__ W3,
                const float* __restrict__ W2,
                float* __restrict__ out,
                int B, int nchunk)
{
    __shared__ __align__(16) bf16 sW2A[16384]; // 32KB W2^T A-frags [(jt*4+kt)*64+l]*8
    __shared__ __align__(16) bf16 sH1 [8192];  // 16KB H1^T B-frags [(st*4+kt)*64+l]*8
    __shared__ __align__(16) bf16 sG2 [8192];  // 16KB G2^T/G1^T B-frags [(st*4+jt2)*64+l]*8
    __shared__ __align__(16) float4 sW1c[HID]; // {W1[0][j],..,W1[3][j]}
    __shared__ float sB1[HID], sB2[HID], sW3[HID];
    __shared__ __align__(16) float sFeat[2][SPB][4];
    __shared__ float sQd[2][SPB][2];
    __shared__ __align__(16) float sDV[4][SPB][4]; // partials per jt2

    const int tid  = threadIdx.x;
    const int w    = tid >> 6;
    const int lane = tid & 63;
    const int lrow = lane & 15;
    const int lq   = lane >> 4;
    const int wlo  = w & 3;
    const int whi  = w >> 2;

    // ---------------- one-time staging ----------------
    if (tid < HID) {
        sW1c[tid] = make_float4(W1[tid], W1[HID + tid], W1[2*HID + tid], W1[3*HID + tid]);
        sB1[tid]  = b1[tid];
    } else if (tid < 2 * HID) {
        sB2[tid - HID] = b2[tid - HID];
        sW3[tid - HID] = W3[tid - HID];
    }
    // W2^T A-frags (column-segment gather), 4 frag lines/thread
    #pragma unroll
    for (int tt = 0; tt < 4; ++tt) {
        int e = tid + tt * TPB;       // 0..2047
        int t = e >> 6, l = e & 63;
        int jt = t >> 2, kt = t & 3;
        int lr = l & 15, q = l >> 4;
        bf16x8 f;
        #pragma unroll
        for (int idx = 0; idx < 8; ++idx)
            f[idx] = (bf16)W2[(32*kt + 8*q + idx) * HID + 16*jt + lr];
        *reinterpret_cast<bf16x8*>(&sW2A[e * 8]) = f;
    }
    // W1 A-frag for GEMM3t, K-range jt2=wlo (rows>=4 zero)
    bf16x8 bW1 = {};
    if (lrow < 4) {
        const float4* wp = reinterpret_cast<const float4*>(&W1[lrow*HID + 32*wlo + 8*lq]);
        float4 a = wp[0], b = wp[1];
        bW1[0]=(bf16)a.x; bW1[1]=(bf16)a.y; bW1[2]=(bf16)a.z; bW1[3]=(bf16)a.w;
        bW1[4]=(bf16)b.x; bW1[5]=(bf16)b.y; bW1[6]=(bf16)b.z; bW1[7]=(bf16)b.w;
    }
    // chunk-0 state prefetch (wave 7)
    if (tid >= TPB - SPB) {
        int s  = tid - (TPB - SPB);
        int g  = (int)blockIdx.x * SPB + s;
        int gc = g < B ? g : (B - 1);
        float4 x = reinterpret_cast<const float4*>(X)[gc];
        float s1, c1, s2, c2;
        __sincosf(x.x, &s1, &c1);
        __sincosf(x.y, &s2, &c2);
        sFeat[0][s][0]=s1; sFeat[0][s][1]=c1; sFeat[0][s][2]=s2; sFeat[0][s][3]=c2;
        sQd[0][s][0]=x.z;  sQd[0][s][1]=x.w;
    }
    __syncthreads();

    #pragma unroll 1
    for (int c = 0; c < nchunk; ++c) {
        const int par = c & 1;
        const int s0  = (c * GRIDB + (int)blockIdx.x) * SPB;

        // ---- Phase 1: H1^T B-frags; tile (st=wlo, kt=2whi+h); lane: s=16wlo+lrow ----
        {
            int s = 16 * wlo + lrow;
            float f0 = sFeat[par][s][0], f1 = sFeat[par][s][1];
            float f2 = sFeat[par][s][2], f3 = sFeat[par][s][3];
            #pragma unroll
            for (int h = 0; h < 2; ++h) {
                int kt = 2 * whi + h;
                int jb = 32 * kt + 8 * lq;
                float4 t0 = *reinterpret_cast<const float4*>(&sB1[jb]);
                float4 t1 = *reinterpret_cast<const float4*>(&sB1[jb + 4]);
                float bias[8] = {t0.x,t0.y,t0.z,t0.w,t1.x,t1.y,t1.z,t1.w};
                bf16x8 hf;
                #pragma unroll
                for (int idx = 0; idx < 8; ++idx) {
                    float4 wc = sW1c[jb + idx];
                    float z = bias[idx] + f0*wc.x + f1*wc.y + f2*wc.z + f3*wc.w;
                    hf[idx] = (bf16)fast_tanh(z);
                }
                *reinterpret_cast<bf16x8*>(&sH1[((wlo*4 + kt)*64 + lane)*8]) = hf;
            }
        }
        __syncthreads(); // B: sH1 ready

        // ---- GEMM1t: Z2^T = W2^T @ H1^T ; out tiles (jt=2wlo+t, st=2whi+s) ----
        floatx4 acc[2][2];
        #pragma unroll
        for (int t = 0; t < 2; ++t)
            #pragma unroll
            for (int s = 0; s < 2; ++s) acc[t][s] = floatx4{0.f,0.f,0.f,0.f};
        #pragma unroll
        for (int kt = 0; kt < 4; ++kt) {
            bf16x8 a0 = *reinterpret_cast<const bf16x8*>(&sW2A[(((2*wlo  )*4 + kt)*64 + lane)*8]);
            bf16x8 a1 = *reinterpret_cast<const bf16x8*>(&sW2A[(((2*wlo+1)*4 + kt)*64 + lane)*8]);
            bf16x8 b0 = *reinterpret_cast<const bf16x8*>(&sH1 [(((2*whi  )*4 + kt)*64 + lane)*8]);
            bf16x8 b1 = *reinterpret_cast<const bf16x8*>(&sH1 [(((2*whi+1)*4 + kt)*64 + lane)*8]);
            acc[0][0] = __builtin_amdgcn_mfma_f32_16x16x32_bf16(a0, b0, acc[0][0], 0,0,0);
            acc[0][1] = __builtin_amdgcn_mfma_f32_16x16x32_bf16(a0, b1, acc[0][1], 0,0,0);
            acc[1][0] = __builtin_amdgcn_mfma_f32_16x16x32_bf16(a1, b0, acc[1][0], 0,0,0);
            acc[1][1] = __builtin_amdgcn_mfma_f32_16x16x32_bf16(a1, b1, acc[1][1], 0,0,0);
        }

        // GEMM2t A-frags: W2 rows from global (L2-hot, transient across phase3)
        bf16x8 aW2[2][4];
        #pragma unroll
        for (int u = 0; u < 2; ++u) {
            const float* rbase = &W2[(16*(2*wlo + u) + lrow) * HID + 8*lq];
            #pragma unroll
            for (int jt2 = 0; jt2 < 4; ++jt2) {
                const float4* rp = reinterpret_cast<const float4*>(rbase + 32*jt2);
                float4 r0 = rp[0], r1 = rp[1];
                bf16x8 g;
                g[0]=(bf16)r0.x; g[1]=(bf16)r0.y; g[2]=(bf16)r0.z; g[3]=(bf16)r0.w;
                g[4]=(bf16)r1.x; g[5]=(bf16)r1.y; g[6]=(bf16)r1.z; g[7]=(bf16)r1.w;
                aW2[u][jt2] = g;
            }
        }

        // ---- Phase 3: G2^T = (1-tanh^2(Z2+b2))*W3 -> B-frags via ds_write_b64 ----
        #pragma unroll
        for (int t = 0; t < 2; ++t) {
            int jb = 16*(2*wlo + t) + 4*lq;   // j for r=0
            float4 b2v = *reinterpret_cast<const float4*>(&sB2[jb]);
            float4 w3v = *reinterpret_cast<const float4*>(&sW3[jb]);
            float bbv[4] = {b2v.x, b2v.y, b2v.z, b2v.w};
            float w3a[4] = {w3v.x, w3v.y, w3v.z, w3v.w};
            int q2  = 2*t + (lq >> 1);
            int sub = 4 * (lq & 1);
            #pragma unroll
            for (int s = 0; s < 2; ++s) {
                int st = 2*whi + s;
                bf16x4 g;
                #pragma unroll
                for (int r = 0; r < 4; ++r) {
                    float h = fast_tanh(acc[t][s][r] + bbv[r]);
                    g[r] = (bf16)((1.0f - h*h) * w3a[r]);
                }
                *reinterpret_cast<bf16x4*>(&sG2[((st*4 + wlo)*64 + (q2*16 + lrow))*8 + sub]) = g;
            }
        }
        __syncthreads(); // C: sG2 (G2^T) ready

        // ---- GEMM2t: S^T = W2 @ G2^T ; out tiles (it=2wlo+u, st=2whi+s) ----
        #pragma unroll
        for (int t = 0; t < 2; ++t)
            #pragma unroll
            for (int s = 0; s < 2; ++s) acc[t][s] = floatx4{0.f,0.f,0.f,0.f};
        #pragma unroll
        for (int jt2 = 0; jt2 < 4; ++jt2) {
            bf16x8 g0 = *reinterpret_cast<const bf16x8*>(&sG2[(((2*whi  )*4 + jt2)*64 + lane)*8]);
            bf16x8 g1 = *reinterpret_cast<const bf16x8*>(&sG2[(((2*whi+1)*4 + jt2)*64 + lane)*8]);
            acc[0][0] = __builtin_amdgcn_mfma_f32_16x16x32_bf16(aW2[0][jt2], g0, acc[0][0], 0,0,0);
            acc[0][1] = __builtin_amdgcn_mfma_f32_16x16x32_bf16(aW2[0][jt2], g1, acc[0][1], 0,0,0);
            acc[1][0] = __builtin_amdgcn_mfma_f32_16x16x32_bf16(aW2[1][jt2], g0, acc[1][0], 0,0,0);
            acc[1][1] = __builtin_amdgcn_mfma_f32_16x16x32_bf16(aW2[1][jt2], g1, acc[1][1], 0,0,0);
        }
        __syncthreads(); // D: all cross-wave sG2 reads done

        // ---- Phase 5: G1^T = (1-h1^2)*S^T, b64 read h1 + b64 write into OWN tile ----
        #pragma unroll
        for (int u = 0; u < 2; ++u) {
            int q2  = 2*u + (lq >> 1);
            int sub = 4 * (lq & 1);
            #pragma unroll
            for (int s = 0; s < 2; ++s) {
                int st  = 2*whi + s;
                int off = ((st*4 + wlo)*64 + (q2*16 + lrow))*8 + sub;
                bf16x4 h4 = *reinterpret_cast<const bf16x4*>(&sH1[off]);
                bf16x4 g;
                #pragma unroll
                for (int r = 0; r < 4; ++r) {
                    float h1 = (float)h4[r];
                    g[r] = (bf16)((1.0f - h1*h1) * acc[u][s][r]);
                }
                *reinterpret_cast<bf16x4*>(&sG2[off]) = g;
            }
        }

        // prefetch next chunk's state (wave 7), overlapped with GEMM3t
        if (tid >= TPB - SPB && c + 1 < nchunk) {
            int s  = tid - (TPB - SPB);
            int g  = ((c + 1) * GRIDB + (int)blockIdx.x) * SPB + s;
            int gc = g < B ? g : (B - 1);
            float4 x = reinterpret_cast<const float4*>(X)[gc];
            float s1, c1, s2, c2;
            __sincosf(x.x, &s1, &c1);
            __sincosf(x.y, &s2, &c2);
            int np = par ^ 1;
            sFeat[np][s][0]=s1; sFeat[np][s][1]=c1; sFeat[np][s][2]=s2; sFeat[np][s][3]=c2;
            sQd[np][s][0]=x.z;  sQd[np][s][1]=x.w;
        }

        // ---- GEMM3t: dV^T partial (jt2=wlo) = W1 @ G1^T (same-wave tiles) ----
        {
            bf16x8 g0 = *reinterpret_cast<const bf16x8*>(&sG2[(((2*whi  )*4 + wlo)*64 + lane)*8]);
            bf16x8 g1 = *reinterpret_cast<const bf16x8*>(&sG2[(((2*whi+1)*4 + wlo)*64 + lane)*8]);
            floatx4 d0 = __builtin_amdgcn_mfma_f32_16x16x32_bf16(bW1, g0, floatx4{0.f,0.f,0.f,0.f}, 0,0,0);
            floatx4 d1 = __builtin_amdgcn_mfma_f32_16x16x32_bf16(bW1, g1, floatx4{0.f,0.f,0.f,0.f}, 0,0,0);
            if (lane < 16) { // quad 0: regs r = dV[k=r] for sample s=16st+lane
                *reinterpret_cast<float4*>(&sDV[wlo][16*(2*whi  ) + lane][0]) =
                    make_float4(d0[0], d0[1], d0[2], d0[3]);
                *reinterpret_cast<float4*>(&sDV[wlo][16*(2*whi+1) + lane][0]) =
                    make_float4(d1[0], d1[1], d1[2], d1[3]);
            }
        }
        __syncthreads(); // F: sDV + next-chunk state visible

        // ---- Epilogue: analytic dynamics + 2x2 solve (wave 0, tid<64) ----
        if (tid < SPB) {
            int g = s0 + tid;
            if (g < B) {
                float4 d0 = *reinterpret_cast<const float4*>(&sDV[0][tid][0]);
                float4 d1 = *reinterpret_cast<const float4*>(&sDV[1][tid][0]);
                float4 d2 = *reinterpret_cast<const float4*>(&sDV[2][tid][0]);
                float4 d3 = *reinterpret_cast<const float4*>(&sDV[3][tid][0]);
                float dV0 = d0.x + d1.x + d2.x + d3.x;
                float dV1 = d0.y + d1.y + d2.y + d3.y;
                float dV2 = d0.z + d1.z + d2.z + d3.z;
                float dV3 = d0.w + d1.w + d2.w + d3.w;
                float s1 = sFeat[par][tid][0], c1 = sFeat[par][tid][1];
                float s2 = sFeat[par][tid][2], c2 = sFeat[par][tid][3];
                float w1 = sQd[par][tid][0],  w2 = sQd[par][tid][1];
                float cosD = c1 * c2 + s1 * s2;
                float sinD = s1 * c2 - c1 * s2;
                float dVt1 = dV0 * c1 - dV1 * s1;   // dV/dt1
                float dVt2 = dV2 * c2 - dV3 * s2;   // dV/dt2
                float sT = w1 * w2 * sinD;          // dT/dt1 = -sT, dT/dt2 = +sT
                float cw = sinD * (w2 - w1);
                float rhs1 = (-sT - dVt1) - w2 * cw;
                float rhs2 = ( sT - dVt2) - w1 * cw;
                float det = 2.0f - cosD * cosD;     // det(M) in [1,2]
                float inv = 1.0f / det;
                float qdd1 = (rhs1 - cosD * rhs2) * inv;
                float qdd2 = (2.0f * rhs2 - cosD * rhs1) * inv;
                *reinterpret_cast<float4*>(&out[4 * g]) = make_float4(w1, w2, qdd1, qdd2);
            }
        }
    }
}

extern "C" void kernel_launch(void* const* d_in, const int* in_sizes, int n_in,
                              void* d_out, int out_size, void* d_ws, size_t ws_size,
                              hipStream_t stream) {
    const float* X  = (const float*)d_in[0];
    const float* W1 = (const float*)d_in[1];
    const float* b1 = (const float*)d_in[2];
    const float* W2 = (const float*)d_in[3];
    const float* b2 = (const float*)d_in[4];
    const float* W3 = (const float*)d_in[5];
    // d_in[6] = b3: constant offset on V, vanishes in all gradients
    float* out = (float*)d_out;
    int B = in_sizes[0] / 4;
    int nchunk = (B + GRIDB * SPB - 1) / (GRIDB * SPB);
    lnn_kernel<<<GRIDB, TPB, 0, stream>>>(X, W1, b1, b2, W3, W2, out, B, nchunk);
}